// Round 8
// baseline (395.186 us; speedup 1.0000x reference)
//
#include <hip/hip_runtime.h>
#include <stdint.h>
#include <stddef.h>

// y[n,o] = sum_i x[n,i]*W[n,i,o] + b[n,o];  W = (x@Ww+bw) reshaped; b = x@Wb+bb.
// Y = A@B (+bb): A[n, j*128+i] = x[n,i]*x[n,j]; B = Ww as [16384,128] row-major;
// K-tail 128: A[n,16384+i]=x[n,i], B[16384+i,o]=Wb[i,o]+bw[i*128+o].
// Per-j-phase factoring: aj = X_rows·B_j (raw-x frags), acc += x[row,j]*aj.
// fp32 in / fp32 out (proven R5/R6); bf16 MFMA compute (absmax 0.25 << 1.35).
// ROUND 8: (1) full-phase B prefetch (8 frags ping-pong — R7 was 1-kstep, ~160cyc
// stall/kstep = the measured 17% MfmaUtil); (2) grid 1024 = 8 slices x 64 rb x 2 cg,
// 4 blocks/CU; (3) finish fused into gemm via per-rb completion counters (2 kernels).

#define NROWS   8192
#define NKT     516            // (16384+128)/32 K-tiles
#define TILE_E  4096           // 128 cols x 32 kk per K-tile image (u16)
#define XS_STRIDE 136          // 128 + 8 pad for LDS x tile
#define LS_STRIDE 136
#define BM      128

typedef unsigned short u16;
typedef short short8 __attribute__((ext_vector_type(8)));
typedef unsigned short ushort8 __attribute__((ext_vector_type(8)));
typedef float floatx4 __attribute__((ext_vector_type(4)));

// Module-scope scratch (BSS; independent of d_ws).
__device__ __align__(16) u16   g_B[(size_t)NKT * TILE_E];   // 4.2 MB bf16 B image
__device__ __align__(16) float g_P[(size_t)NROWS * 128];    // 4 MB fp32 partials
__device__ int g_cnt[64];                                   // per-rowblock completion

__device__ __forceinline__ u16 f2bf_rne(float f) {
    unsigned int u = __float_as_uint(f);
    u += 0x7fffu + ((u >> 16) & 1u);
    return (u16)(u >> 16);
}

// ---------------- prep: g_B[kt][o][kk] = B[kt*32+kk][o] via LDS transpose;
//                  zeroes g_P and g_cnt ----------------
__global__ __launch_bounds__(256) void prep_kernel(
    const float* __restrict__ Ww, const float* __restrict__ Wb,
    const float* __restrict__ bw)
{
    __shared__ __align__(16) u16 ls[32 * LS_STRIDE];
    const int kt = blockIdx.x;
    const int t  = threadIdx.x;

    if (kt < 512) {                       // zero g_P (8KB per block)
        const int zbase = (kt*256 + t) * 8;
        const floatx4 z = {0.f, 0.f, 0.f, 0.f};
        *(floatx4*)&g_P[zbase]     = z;
        *(floatx4*)&g_P[zbase + 4] = z;
    }
    if (kt < 64 && t == 0) g_cnt[kt] = 0; // zero completion counters

    float v[16];
    if (kt < 512) {
        const float* src = Ww + (size_t)(kt >> 2)*16384 + (size_t)(kt & 3)*32*128 + t*16;
#pragma unroll
        for (int c = 0; c < 4; ++c) {
            const floatx4 f4 = *(const floatx4*)(src + c*4);
#pragma unroll
            for (int e = 0; e < 4; ++e) v[c*4 + e] = f4[e];
        }
    } else {
        const size_t base = (size_t)(kt - 512)*32*128 + t*16;
#pragma unroll
        for (int c = 0; c < 4; ++c) {
            const floatx4 a = *(const floatx4*)(Wb + base + c*4);
            const floatx4 b = *(const floatx4*)(bw + base + c*4);
#pragma unroll
            for (int e = 0; e < 4; ++e) v[c*4 + e] = a[e] + b[e];
        }
    }
    {
        const int kk = t >> 3;
        const int o0 = (t & 7) * 16;
        ushort8 w0, w1;
#pragma unroll
        for (int e = 0; e < 8; ++e) { w0[e] = f2bf_rne(v[e]); w1[e] = f2bf_rne(v[8+e]); }
        *(ushort8*)&ls[kk*LS_STRIDE + o0]     = w0;
        *(ushort8*)&ls[kk*LS_STRIDE + o0 + 8] = w1;
    }
    __syncthreads();
    {
        const int o   = t >> 1;
        const int kk0 = (t & 1) * 16;
        ushort8 w0, w1;
#pragma unroll
        for (int e = 0; e < 8; ++e) {
            w0[e] = ls[(kk0 + e)*LS_STRIDE + o];
            w1[e] = ls[(kk0 + 8 + e)*LS_STRIDE + o];
        }
        u16* outp = g_B + (size_t)kt*TILE_E + t*16;
        ((ushort8*)outp)[0] = w0; ((ushort8*)outp)[1] = w1;
    }
}

// ---------------- gemm: full-phase prefetch + fused finish ----------------
// grid 1024: slice = b&7 (XCD-pinned), rb = (b>>3)&63, cg = b>>9.
__global__ __launch_bounds__(256, 4) void gemm_kernel(
    const float* __restrict__ x, const float* __restrict__ bb,
    float* __restrict__ out)
{
    __shared__ __align__(16) u16 xs[BM * XS_STRIDE];
    __shared__ int s_last;

    const int b     = blockIdx.x;
    const int slice = b & 7;
    const int rb    = (b >> 3) & 63;
    const int cg    = b >> 9;
    const int row0  = rb * BM;
    const int tid   = threadIdx.x;
    const int lane  = tid & 63;
    const int wave  = tid >> 6;
    const int wm    = wave >> 1;
    const int wc    = wave & 1;
    const int l15   = lane & 15;
    const int q     = lane >> 4;

    // stage x rows fp32 -> bf16 xs
#pragma unroll
    for (int it = 0; it < 8; ++it) {
        const int c  = it*256 + tid;
        const int r  = c >> 4;
        const int c8 = (c & 15) * 8;
        const float* sp = x + ((size_t)(row0 + r) << 7) + c8;
        const floatx4 f0 = *(const floatx4*)(sp);
        const floatx4 f1 = *(const floatx4*)(sp + 4);
        ushort8 w;
#pragma unroll
        for (int e = 0; e < 4; ++e) { w[e] = f2bf_rne(f0[e]); w[4+e] = f2bf_rne(f1[e]); }
        *(ushort8*)&xs[r*XS_STRIDE + c8] = w;
    }
    __syncthreads();

    short8 af[4][4];                    // A[m=l15][k=q*8+e], phase-invariant
#pragma unroll
    for (int ks = 0; ks < 4; ++ks)
#pragma unroll
        for (int mt = 0; mt < 4; ++mt)
            af[ks][mt] = *(const short8*)&xs[(wm*64 + mt*16 + l15)*XS_STRIDE + ks*32 + q*8];

    const floatx4 fzero = {0.f, 0.f, 0.f, 0.f};
    floatx4 acc[4][2];
#pragma unroll
    for (int i = 0; i < 4; ++i) { acc[i][0] = fzero; acc[i][1] = fzero; }

    // phases: slice 0 -> 0..16 (17), slice s>0 -> 16s+1 .. +16
    const int p0 = slice*16 + (slice ? 1 : 0);
    const int np = (slice == 0) ? 17 : 16;
    const int pend = p0 + np - 1;

    const int colbase = cg*64 + wc*32;
    const size_t loff = (size_t)(colbase + l15)*32 + q*8;

    auto loadPhase = [&](int p, short8 (&buf)[4][2]) {
#pragma unroll
        for (int ks = 0; ks < 4; ++ks) {
            const u16* tb = g_B + (size_t)(p*4 + ks)*TILE_E + loff;
            buf[ks][0] = *(const short8*)(tb);
            buf[ks][1] = *(const short8*)(tb + 512);
        }
    };

    short8 bufA[4][2], bufB[4][2];
    loadPhase(p0, bufA);

    auto phase = [&](int p, short8 (&CUR)[4][2], short8 (&NXT)[4][2]) {
        const int pf = (p + 1 <= pend) ? p + 1 : pend;
        loadPhase(pf, NXT);             // full-phase prefetch: 8 loads in flight
        floatx4 aj[4][2];
#pragma unroll
        for (int i = 0; i < 4; ++i) { aj[i][0] = fzero; aj[i][1] = fzero; }
#pragma unroll
        for (int ks = 0; ks < 4; ++ks)
#pragma unroll
            for (int mt = 0; mt < 4; ++mt) {
                aj[mt][0] = __builtin_amdgcn_mfma_f32_16x16x32_bf16(af[ks][mt], CUR[ks][0], aj[mt][0], 0,0,0);
                aj[mt][1] = __builtin_amdgcn_mfma_f32_16x16x32_bf16(af[ks][mt], CUR[ks][1], aj[mt][1], 0,0,0);
            }
#pragma unroll
        for (int mt = 0; mt < 4; ++mt)
#pragma unroll
            for (int r = 0; r < 4; ++r) {
                const int rl = wm*64 + mt*16 + q*4 + r;     // C/D: row = q*4+reg
                float xj = 1.0f;
                if (p < 128)
                    xj = __uint_as_float(((unsigned int)xs[rl*XS_STRIDE + p]) << 16);
                acc[mt][0][r] += xj * aj[mt][0][r];
                acc[mt][1][r] += xj * aj[mt][1][r];
            }
    };

    for (int pp = 0; pp < np; pp += 2) {
        phase(p0 + pp, bufA, bufB);
        if (pp + 1 < np) phase(p0 + pp + 1, bufB, bufA);
    }

    // reduce into g_P (device-scope atomics)
#pragma unroll
    for (int mt = 0; mt < 4; ++mt)
#pragma unroll
        for (int nt = 0; nt < 2; ++nt) {
            const int col = colbase + nt*16 + l15;
#pragma unroll
            for (int r = 0; r < 4; ++r) {
                const int row = row0 + wm*64 + mt*16 + q*4 + r;
                atomicAdd(&g_P[((size_t)row << 7) + col], acc[mt][nt][r]);
            }
        }
    __syncthreads();                    // barrier drains vmcnt: block's atomics done
    if (tid == 0) {
        __threadfence();                // release
        s_last = (atomicAdd(&g_cnt[rb], 1) == 15) ? 1 : 0;
    }
    __syncthreads();
    if (s_last) {                       // 16th block for this rb: finish 128 rows
        __threadfence();                // acquire
        const float bv = bb[tid & 127];
#pragma unroll 4
        for (int it = 0; it < 64; ++it) {
            const size_t idx = (size_t)row0*128 + it*256 + tid;
            const float v = __hip_atomic_load(&g_P[idx], __ATOMIC_RELAXED,
                                              __HIP_MEMORY_SCOPE_AGENT);
            out[idx] = v + bv;
        }
    }
}

extern "C" void kernel_launch(void* const* d_in, const int* in_sizes, int n_in,
                              void* d_out, int out_size, void* d_ws, size_t ws_size,
                              hipStream_t stream) {
    (void)in_sizes; (void)n_in; (void)out_size; (void)d_ws; (void)ws_size;
    const float* x  = (const float*)d_in[0];
    const float* Wb = (const float*)d_in[1];
    const float* bb = (const float*)d_in[2];
    const float* Ww = (const float*)d_in[3];
    const float* bw = (const float*)d_in[4];
    float* out = (float*)d_out;

    prep_kernel<<<dim3(NKT),  dim3(256), 0, stream>>>(Ww, Wb, bw);
    gemm_kernel<<<dim3(1024), dim3(256), 0, stream>>>(x, bb, out);
}

// Round 9
// 221.383 us; speedup vs baseline: 1.7851x; 1.7851x over previous
//
#include <hip/hip_runtime.h>
#include <stdint.h>
#include <stddef.h>

// y[n,o] = sum_i x[n,i]*W[n,i,o] + b[n,o];  W = (x@Ww+bw) reshaped; b = x@Wb+bb.
// Y = A@B (+bb): A[n, j*128+i] = x[n,i]*x[n,j]; B = Ww as [16384,128] row-major;
// K-tail 128: A[n,16384+i]=x[n,i], B[16384+i,o]=Wb[i,o]+bw[i*128+o].
// Per-j-phase factoring: aj = X_rows·B_j (raw-x frags), acc += x[row,j]*aj.
// fp32 in / fp32 out; bf16 MFMA compute (absmax 0.25 << 1.35).
// ROUND 9: R7 structure (78.6us, 80 VGPR — proven no-spill) + (a) pair-granularity
// depth-2 prefetch (+16 VGPR only; R8's 64-VGPR full-phase buffers spilled:
// FETCH 12.6->538MB, MfmaUtil 3%), (b) grid 1024 = 8 XCD-pinned slices x 64 rb x
// 2 cg, (c) R8's proven fused finish via completion counters (2 kernels total).

#define NROWS   8192
#define NKT     516            // (16384+128)/32 K-tiles
#define TILE_E  4096           // 128 cols x 32 kk per K-tile image (u16)
#define XS_STRIDE 136          // 128 + 8 pad for LDS x tile
#define LS_STRIDE 136
#define BM      128

typedef unsigned short u16;
typedef short short8 __attribute__((ext_vector_type(8)));
typedef unsigned short ushort8 __attribute__((ext_vector_type(8)));
typedef float floatx4 __attribute__((ext_vector_type(4)));

// Module-scope scratch (BSS; independent of d_ws).
__device__ __align__(16) u16   g_B[(size_t)NKT * TILE_E];   // 4.2 MB bf16 B image
__device__ __align__(16) float g_P[(size_t)NROWS * 128];    // 4 MB fp32 partials
__device__ int g_cnt[64];                                   // per-rowblock completion

__device__ __forceinline__ u16 f2bf_rne(float f) {
    unsigned int u = __float_as_uint(f);
    u += 0x7fffu + ((u >> 16) & 1u);
    return (u16)(u >> 16);
}

// ---------------- prep: g_B[kt][o][kk] = B[kt*32+kk][o] via LDS transpose;
//                  zeroes g_P and g_cnt ----------------
__global__ __launch_bounds__(256) void prep_kernel(
    const float* __restrict__ Ww, const float* __restrict__ Wb,
    const float* __restrict__ bw)
{
    __shared__ __align__(16) u16 ls[32 * LS_STRIDE];
    const int kt = blockIdx.x;
    const int t  = threadIdx.x;

    if (kt < 512) {                       // zero g_P (8KB per block)
        const int zbase = (kt*256 + t) * 8;
        const floatx4 z = {0.f, 0.f, 0.f, 0.f};
        *(floatx4*)&g_P[zbase]     = z;
        *(floatx4*)&g_P[zbase + 4] = z;
    }
    if (kt < 64 && t == 0) g_cnt[kt] = 0; // zero completion counters

    float v[16];
    if (kt < 512) {
        const float* src = Ww + (size_t)(kt >> 2)*16384 + (size_t)(kt & 3)*32*128 + t*16;
#pragma unroll
        for (int c = 0; c < 4; ++c) {
            const floatx4 f4 = *(const floatx4*)(src + c*4);
#pragma unroll
            for (int e = 0; e < 4; ++e) v[c*4 + e] = f4[e];
        }
    } else {
        const size_t base = (size_t)(kt - 512)*32*128 + t*16;
#pragma unroll
        for (int c = 0; c < 4; ++c) {
            const floatx4 a = *(const floatx4*)(Wb + base + c*4);
            const floatx4 b = *(const floatx4*)(bw + base + c*4);
#pragma unroll
            for (int e = 0; e < 4; ++e) v[c*4 + e] = a[e] + b[e];
        }
    }
    {
        const int kk = t >> 3;
        const int o0 = (t & 7) * 16;
        ushort8 w0, w1;
#pragma unroll
        for (int e = 0; e < 8; ++e) { w0[e] = f2bf_rne(v[e]); w1[e] = f2bf_rne(v[8+e]); }
        *(ushort8*)&ls[kk*LS_STRIDE + o0]     = w0;
        *(ushort8*)&ls[kk*LS_STRIDE + o0 + 8] = w1;
    }
    __syncthreads();
    {
        const int o   = t >> 1;
        const int kk0 = (t & 1) * 16;
        ushort8 w0, w1;
#pragma unroll
        for (int e = 0; e < 8; ++e) {
            w0[e] = ls[(kk0 + e)*LS_STRIDE + o];
            w1[e] = ls[(kk0 + 8 + e)*LS_STRIDE + o];
        }
        u16* outp = g_B + (size_t)kt*TILE_E + t*16;
        ((ushort8*)outp)[0] = w0; ((ushort8*)outp)[1] = w1;
    }
}

// ---------------- gemm: depth-2 (pair) prefetch + fused finish ----------------
// grid 1024: slice = b&7 (XCD-pinned), rb = (b>>3)&63, cg = b>>9.
__global__ __launch_bounds__(256, 3) void gemm_kernel(
    const float* __restrict__ x, const float* __restrict__ bb,
    float* __restrict__ out)
{
    __shared__ __align__(16) u16 xs[BM * XS_STRIDE];
    __shared__ int s_last;

    const int b     = blockIdx.x;
    const int slice = b & 7;
    const int rb    = (b >> 3) & 63;
    const int cg    = b >> 9;
    const int row0  = rb * BM;
    const int tid   = threadIdx.x;
    const int lane  = tid & 63;
    const int wave  = tid >> 6;
    const int wm    = wave >> 1;
    const int wc    = wave & 1;
    const int l15   = lane & 15;
    const int q     = lane >> 4;

    // stage x rows fp32 -> bf16 xs
#pragma unroll
    for (int it = 0; it < 8; ++it) {
        const int c  = it*256 + tid;
        const int r  = c >> 4;
        const int c8 = (c & 15) * 8;
        const float* sp = x + ((size_t)(row0 + r) << 7) + c8;
        const floatx4 f0 = *(const floatx4*)(sp);
        const floatx4 f1 = *(const floatx4*)(sp + 4);
        ushort8 w;
#pragma unroll
        for (int e = 0; e < 4; ++e) { w[e] = f2bf_rne(f0[e]); w[4+e] = f2bf_rne(f1[e]); }
        *(ushort8*)&xs[r*XS_STRIDE + c8] = w;
    }
    __syncthreads();

    short8 af[4][4];                    // A[m=l15][k=q*8+e], phase-invariant
#pragma unroll
    for (int ks = 0; ks < 4; ++ks)
#pragma unroll
        for (int mt = 0; mt < 4; ++mt)
            af[ks][mt] = *(const short8*)&xs[(wm*64 + mt*16 + l15)*XS_STRIDE + ks*32 + q*8];

    const floatx4 fzero = {0.f, 0.f, 0.f, 0.f};
    floatx4 acc[4][2];
#pragma unroll
    for (int i = 0; i < 4; ++i) { acc[i][0] = fzero; acc[i][1] = fzero; }

    // phases: slice 0 -> 0..16 (17), slice s>0 -> 16s+1 .. +16
    const int p0 = slice*16 + (slice ? 1 : 0);
    const int np = (slice == 0) ? 17 : 16;

    const int colbase = cg*64 + wc*32;
    const size_t loff = (size_t)(colbase + l15)*32 + q*8;
    const int ktN = (p0 + np)*4;        // one past last kstep

    // load a PAIR of consecutive ksteps (4 frags = 16 VGPR)
    auto LOADP = [&](int ktp, short8 (&buf)[2][2]) {
        const u16* tb0 = g_B + (size_t)ktp*TILE_E + loff;
        buf[0][0] = *(const short8*)(tb0);
        buf[0][1] = *(const short8*)(tb0 + 512);
        const u16* tb1 = tb0 + TILE_E;
        buf[1][0] = *(const short8*)(tb1);
        buf[1][1] = *(const short8*)(tb1 + 512);
    };

    short8 bufA[2][2], bufB[2][2];
    int kt = p0*4;
    LOADP(kt, bufA);                    // pair (kt, kt+1)

    for (int pp = 0; pp < np; ++pp) {
        const int p = p0 + pp;
        floatx4 aj[4][2];
#pragma unroll
        for (int i = 0; i < 4; ++i) { aj[i][0] = fzero; aj[i][1] = fzero; }

        LOADP(kt + 2, bufB);            // prefetch pair 1 of this phase
#pragma unroll
        for (int s = 0; s < 2; ++s)
#pragma unroll
            for (int mt = 0; mt < 4; ++mt) {
                aj[mt][0] = __builtin_amdgcn_mfma_f32_16x16x32_bf16(af[s][mt], bufA[s][0], aj[mt][0], 0,0,0);
                aj[mt][1] = __builtin_amdgcn_mfma_f32_16x16x32_bf16(af[s][mt], bufA[s][1], aj[mt][1], 0,0,0);
            }
        const int ktn = (kt + 4 <= ktN - 2) ? kt + 4 : ktN - 2;
        LOADP(ktn, bufA);               // prefetch next phase's pair 0
#pragma unroll
        for (int s = 0; s < 2; ++s)
#pragma unroll
            for (int mt = 0; mt < 4; ++mt) {
                aj[mt][0] = __builtin_amdgcn_mfma_f32_16x16x32_bf16(af[2+s][mt], bufB[s][0], aj[mt][0], 0,0,0);
                aj[mt][1] = __builtin_amdgcn_mfma_f32_16x16x32_bf16(af[2+s][mt], bufB[s][1], aj[mt][1], 0,0,0);
            }
        kt += 4;

        // acc += x_bf16[row, p] * aj   (tail phase p==128: scale 1 -> Wb+bw term)
#pragma unroll
        for (int mt = 0; mt < 4; ++mt)
#pragma unroll
            for (int r = 0; r < 4; ++r) {
                const int rl = wm*64 + mt*16 + q*4 + r;     // C/D: row = q*4+reg
                float xj = 1.0f;
                if (p < 128)
                    xj = __uint_as_float(((unsigned int)xs[rl*XS_STRIDE + p]) << 16);
                acc[mt][0][r] += xj * aj[mt][0][r];
                acc[mt][1][r] += xj * aj[mt][1][r];
            }
    }

    // reduce into g_P (device-scope atomics)
#pragma unroll
    for (int mt = 0; mt < 4; ++mt)
#pragma unroll
        for (int nt = 0; nt < 2; ++nt) {
            const int col = colbase + nt*16 + l15;
#pragma unroll
            for (int r = 0; r < 4; ++r) {
                const int row = row0 + wm*64 + mt*16 + q*4 + r;
                atomicAdd(&g_P[((size_t)row << 7) + col], acc[mt][nt][r]);
            }
        }
    __syncthreads();                    // block's atomics issued & drained
    if (tid == 0) {
        __threadfence();                // release
        s_last = (atomicAdd(&g_cnt[rb], 1) == 15) ? 1 : 0;
    }
    __syncthreads();
    if (s_last) {                       // 16th block for this rb: finish 128 rows
        __threadfence();                // acquire
        const float bv = bb[tid & 127];
#pragma unroll 4
        for (int it = 0; it < 64; ++it) {
            const size_t idx = (size_t)row0*128 + it*256 + tid;
            const float v = __hip_atomic_load(&g_P[idx], __ATOMIC_RELAXED,
                                              __HIP_MEMORY_SCOPE_AGENT);
            out[idx] = v + bv;
        }
    }
}

extern "C" void kernel_launch(void* const* d_in, const int* in_sizes, int n_in,
                              void* d_out, int out_size, void* d_ws, size_t ws_size,
                              hipStream_t stream) {
    (void)in_sizes; (void)n_in; (void)out_size; (void)d_ws; (void)ws_size;
    const float* x  = (const float*)d_in[0];
    const float* Wb = (const float*)d_in[1];
    const float* bb = (const float*)d_in[2];
    const float* Ww = (const float*)d_in[3];
    const float* bw = (const float*)d_in[4];
    float* out = (float*)d_out;

    prep_kernel<<<dim3(NKT),  dim3(256), 0, stream>>>(Ww, Wb, bw);
    gemm_kernel<<<dim3(1024), dim3(256), 0, stream>>>(x, bb, out);
}

// Round 10
// 215.873 us; speedup vs baseline: 1.8306x; 1.0255x over previous
//
#include <hip/hip_runtime.h>
#include <stdint.h>
#include <stddef.h>

// y[n,o] = sum_i x[n,i]*W[n,i,o] + b[n,o];  W = (x@Ww+bw) reshaped; b = x@Wb+bb.
// Y = A@B (+bb): A[n, j*128+i] = x[n,i]*x[n,j]; B = Ww as [16384,128] row-major;
// K-tail 128: A[n,16384+i]=x[n,i], B[16384+i,o]=Wb[i,o]+bw[i*128+o].
// Per-j-phase factoring: aj = X_rows·B_j (raw-x frags), acc += x[row,j]*aj.
// fp32 in / fp32 out; bf16 MFMA compute (absmax 0.25 << 1.35).
// ROUND 10: R9 exactly, except x is pre-converted to a bf16 image g_X (2 MB) so the
// slice-pinned per-XCD L2 set = 2.0(x) + 0.53(B) < 4 MB. R9's FETCH 32.8MB == 8 XCD
// x 4MB fp32-x proved the x stream was evicting the B slice -> B frags fell to
// L3/HBM latency (MfmaUtil 8%). R7 had the dual problem (all-slices B 4.2MB/XCD).

#define NROWS   8192
#define NKT     516            // (16384+128)/32 K-tiles
#define TILE_E  4096           // 128 cols x 32 kk per K-tile image (u16)
#define XS_STRIDE 136          // 128 + 8 pad for LDS x tile
#define LS_STRIDE 136
#define BM      128

typedef unsigned short u16;
typedef short short8 __attribute__((ext_vector_type(8)));
typedef unsigned short ushort8 __attribute__((ext_vector_type(8)));
typedef float floatx4 __attribute__((ext_vector_type(4)));

// Module-scope scratch (BSS; independent of d_ws).
__device__ __align__(16) u16   g_B[(size_t)NKT * TILE_E];   // 4.2 MB bf16 B image
__device__ __align__(16) u16   g_X[(size_t)NROWS * 128];    // 2 MB bf16 x image
__device__ __align__(16) float g_P[(size_t)NROWS * 128];    // 4 MB fp32 partials
__device__ int g_cnt[64];                                   // per-rowblock completion

__device__ __forceinline__ u16 f2bf_rne(float f) {
    unsigned int u = __float_as_uint(f);
    u += 0x7fffu + ((u >> 16) & 1u);
    return (u16)(u >> 16);
}

// ---------------- prep: g_B[kt][o][kk] = B[kt*32+kk][o] via LDS transpose;
//                  also g_X = bf16(x), zero g_P and g_cnt ----------------
__global__ __launch_bounds__(256) void prep_kernel(
    const float* __restrict__ Ww, const float* __restrict__ Wb,
    const float* __restrict__ bw, const float* __restrict__ x)
{
    __shared__ __align__(16) u16 ls[32 * LS_STRIDE];
    const int kt = blockIdx.x;
    const int t  = threadIdx.x;

    if (kt < 512) {                       // zero g_P (8KB per block)
        const int zbase = (kt*256 + t) * 8;
        const floatx4 z = {0.f, 0.f, 0.f, 0.f};
        *(floatx4*)&g_P[zbase]     = z;
        *(floatx4*)&g_P[zbase + 4] = z;
        // convert x -> g_X bf16 (2048 elems per block)
        const int xb = kt*2048 + t*8;
        const floatx4 xa = *(const floatx4*)(x + xb);
        const floatx4 xc = *(const floatx4*)(x + xb + 4);
        ushort8 xw;
#pragma unroll
        for (int e = 0; e < 4; ++e) { xw[e] = f2bf_rne(xa[e]); xw[4+e] = f2bf_rne(xc[e]); }
        *(ushort8*)&g_X[xb] = xw;
    }
    if (kt < 64 && t == 0) g_cnt[kt] = 0; // zero completion counters

    float v[16];
    if (kt < 512) {
        const float* src = Ww + (size_t)(kt >> 2)*16384 + (size_t)(kt & 3)*32*128 + t*16;
#pragma unroll
        for (int c = 0; c < 4; ++c) {
            const floatx4 f4 = *(const floatx4*)(src + c*4);
#pragma unroll
            for (int e = 0; e < 4; ++e) v[c*4 + e] = f4[e];
        }
    } else {
        const size_t base = (size_t)(kt - 512)*32*128 + t*16;
#pragma unroll
        for (int c = 0; c < 4; ++c) {
            const floatx4 a = *(const floatx4*)(Wb + base + c*4);
            const floatx4 b = *(const floatx4*)(bw + base + c*4);
#pragma unroll
            for (int e = 0; e < 4; ++e) v[c*4 + e] = a[e] + b[e];
        }
    }
    {
        const int kk = t >> 3;
        const int o0 = (t & 7) * 16;
        ushort8 w0, w1;
#pragma unroll
        for (int e = 0; e < 8; ++e) { w0[e] = f2bf_rne(v[e]); w1[e] = f2bf_rne(v[8+e]); }
        *(ushort8*)&ls[kk*LS_STRIDE + o0]     = w0;
        *(ushort8*)&ls[kk*LS_STRIDE + o0 + 8] = w1;
    }
    __syncthreads();
    {
        const int o   = t >> 1;
        const int kk0 = (t & 1) * 16;
        ushort8 w0, w1;
#pragma unroll
        for (int e = 0; e < 8; ++e) {
            w0[e] = ls[(kk0 + e)*LS_STRIDE + o];
            w1[e] = ls[(kk0 + 8 + e)*LS_STRIDE + o];
        }
        u16* outp = g_B + (size_t)kt*TILE_E + t*16;
        ((ushort8*)outp)[0] = w0; ((ushort8*)outp)[1] = w1;
    }
}

// ---------------- gemm: depth-2 (pair) prefetch + fused finish ----------------
// grid 1024: slice = b&7 (XCD-pinned), rb = (b>>3)&63, cg = b>>9.
__global__ __launch_bounds__(256, 3) void gemm_kernel(
    const float* __restrict__ bb, float* __restrict__ out)
{
    __shared__ __align__(16) u16 xs[BM * XS_STRIDE];
    __shared__ int s_last;

    const int b     = blockIdx.x;
    const int slice = b & 7;
    const int rb    = (b >> 3) & 63;
    const int cg    = b >> 9;
    const int row0  = rb * BM;
    const int tid   = threadIdx.x;
    const int lane  = tid & 63;
    const int wave  = tid >> 6;
    const int wm    = wave >> 1;
    const int wc    = wave & 1;
    const int l15   = lane & 15;
    const int q     = lane >> 4;

    // stage x rows from bf16 g_X (32 KB per block)
#pragma unroll
    for (int it = 0; it < 8; ++it) {
        const int c  = it*256 + tid;
        const int r  = c >> 4;
        const int c8 = (c & 15) * 8;
        *(ushort8*)&xs[r*XS_STRIDE + c8] =
            *(const ushort8*)&g_X[((size_t)(row0 + r) << 7) + c8];
    }
    __syncthreads();

    short8 af[4][4];                    // A[m=l15][k=q*8+e], phase-invariant
#pragma unroll
    for (int ks = 0; ks < 4; ++ks)
#pragma unroll
        for (int mt = 0; mt < 4; ++mt)
            af[ks][mt] = *(const short8*)&xs[(wm*64 + mt*16 + l15)*XS_STRIDE + ks*32 + q*8];

    const floatx4 fzero = {0.f, 0.f, 0.f, 0.f};
    floatx4 acc[4][2];
#pragma unroll
    for (int i = 0; i < 4; ++i) { acc[i][0] = fzero; acc[i][1] = fzero; }

    // phases: slice 0 -> 0..16 (17), slice s>0 -> 16s+1 .. +16
    const int p0 = slice*16 + (slice ? 1 : 0);
    const int np = (slice == 0) ? 17 : 16;

    const int colbase = cg*64 + wc*32;
    const size_t loff = (size_t)(colbase + l15)*32 + q*8;
    const int ktN = (p0 + np)*4;        // one past last kstep

    // load a PAIR of consecutive ksteps (4 frags = 16 VGPR)
    auto LOADP = [&](int ktp, short8 (&buf)[2][2]) {
        const u16* tb0 = g_B + (size_t)ktp*TILE_E + loff;
        buf[0][0] = *(const short8*)(tb0);
        buf[0][1] = *(const short8*)(tb0 + 512);
        const u16* tb1 = tb0 + TILE_E;
        buf[1][0] = *(const short8*)(tb1);
        buf[1][1] = *(const short8*)(tb1 + 512);
    };

    short8 bufA[2][2], bufB[2][2];
    int kt = p0*4;
    LOADP(kt, bufA);                    // pair (kt, kt+1)

    for (int pp = 0; pp < np; ++pp) {
        const int p = p0 + pp;
        floatx4 aj[4][2];
#pragma unroll
        for (int i = 0; i < 4; ++i) { aj[i][0] = fzero; aj[i][1] = fzero; }

        LOADP(kt + 2, bufB);            // prefetch pair 1 of this phase
#pragma unroll
        for (int s = 0; s < 2; ++s)
#pragma unroll
            for (int mt = 0; mt < 4; ++mt) {
                aj[mt][0] = __builtin_amdgcn_mfma_f32_16x16x32_bf16(af[s][mt], bufA[s][0], aj[mt][0], 0,0,0);
                aj[mt][1] = __builtin_amdgcn_mfma_f32_16x16x32_bf16(af[s][mt], bufA[s][1], aj[mt][1], 0,0,0);
            }
        const int ktn = (kt + 4 <= ktN - 2) ? kt + 4 : ktN - 2;
        LOADP(ktn, bufA);               // prefetch next phase's pair 0
#pragma unroll
        for (int s = 0; s < 2; ++s)
#pragma unroll
            for (int mt = 0; mt < 4; ++mt) {
                aj[mt][0] = __builtin_amdgcn_mfma_f32_16x16x32_bf16(af[2+s][mt], bufB[s][0], aj[mt][0], 0,0,0);
                aj[mt][1] = __builtin_amdgcn_mfma_f32_16x16x32_bf16(af[2+s][mt], bufB[s][1], aj[mt][1], 0,0,0);
            }
        kt += 4;

        // acc += x_bf16[row, p] * aj   (tail phase p==128: scale 1 -> Wb+bw term)
#pragma unroll
        for (int mt = 0; mt < 4; ++mt)
#pragma unroll
            for (int r = 0; r < 4; ++r) {
                const int rl = wm*64 + mt*16 + q*4 + r;     // C/D: row = q*4+reg
                float xj = 1.0f;
                if (p < 128)
                    xj = __uint_as_float(((unsigned int)xs[rl*XS_STRIDE + p]) << 16);
                acc[mt][0][r] += xj * aj[mt][0][r];
                acc[mt][1][r] += xj * aj[mt][1][r];
            }
    }

    // reduce into g_P (device-scope atomics)
#pragma unroll
    for (int mt = 0; mt < 4; ++mt)
#pragma unroll
        for (int nt = 0; nt < 2; ++nt) {
            const int col = colbase + nt*16 + l15;
#pragma unroll
            for (int r = 0; r < 4; ++r) {
                const int row = row0 + wm*64 + mt*16 + q*4 + r;
                atomicAdd(&g_P[((size_t)row << 7) + col], acc[mt][nt][r]);
            }
        }
    __syncthreads();                    // block's atomics issued & drained
    if (tid == 0) {
        __threadfence();                // release
        s_last = (atomicAdd(&g_cnt[rb], 1) == 15) ? 1 : 0;
    }
    __syncthreads();
    if (s_last) {                       // 16th block for this rb: finish 128 rows
        __threadfence();                // acquire
        const float bv = bb[tid & 127];
#pragma unroll 4
        for (int it = 0; it < 64; ++it) {
            const size_t idx = (size_t)row0*128 + it*256 + tid;
            const float v = __hip_atomic_load(&g_P[idx], __ATOMIC_RELAXED,
                                              __HIP_MEMORY_SCOPE_AGENT);
            out[idx] = v + bv;
        }
    }
}

extern "C" void kernel_launch(void* const* d_in, const int* in_sizes, int n_in,
                              void* d_out, int out_size, void* d_ws, size_t ws_size,
                              hipStream_t stream) {
    (void)in_sizes; (void)n_in; (void)out_size; (void)d_ws; (void)ws_size;
    const float* x  = (const float*)d_in[0];
    const float* Wb = (const float*)d_in[1];
    const float* bb = (const float*)d_in[2];
    const float* Ww = (const float*)d_in[3];
    const float* bw = (const float*)d_in[4];
    float* out = (float*)d_out;

    prep_kernel<<<dim3(NKT),  dim3(256), 0, stream>>>(Ww, Wb, bw, x);
    gemm_kernel<<<dim3(1024), dim3(256), 0, stream>>>(bb, out);
}